// Round 12
// baseline (180.893 us; speedup 1.0000x reference)
//
#include <hip/hip_runtime.h>
#include <stdint.h>

typedef unsigned short u16;
typedef short bf16x8 __attribute__((ext_vector_type(8)));
typedef short s16x4 __attribute__((ext_vector_type(4)));
typedef unsigned short u16x4 __attribute__((ext_vector_type(4)));
typedef float f32x4 __attribute__((ext_vector_type(4)));

#define NROW 4096
#define LDW 72  // LDS row stride (u16) for 64x64 tiles (stride-72: 2-way max, free)
#define RDW 68  // redbuf row stride (f32): breaks quad-stride bank aliasing
#define SLICE 262144  // 4096*64 floats per partial slice

// round-to-nearest-even float -> bf16 bits (x, U: fidelity matters)
__device__ __forceinline__ u16 f2bf(float f) {
  uint32_t u = __float_as_uint(f);
  u = (u + 0x7fffu + ((u >> 16) & 1u)) >> 16;
  return (u16)u;
}

// truncating float -> bf16 (weights only: bias cancels between num and den)
__device__ __forceinline__ u16 f2bf_t(float f) {
  return (u16)(__float_as_uint(f) >> 16);
}

__device__ __forceinline__ f32x4 mfma16(bf16x8 a, bf16x8 b, f32x4 c) {
  return __builtin_amdgcn_mfma_f32_16x16x32_bf16(a, b, c, 0, 0, 0);
}

// chained second-GEMM MFMA: the 16x16x32 C-fragment (row=quad*4+r, col=l16) is
// exactly the 16x16x16 A-operand layout (row=lane&15, k=(lane>>4)*4+reg), so the
// weight fragment feeds this with NO LDS transpose.
__device__ __forceinline__ f32x4 mfma16k(s16x4 a, s16x4 b, f32x4 c) {
  return __builtin_amdgcn_mfma_f32_16x16x16bf16_1k(a, b, c, 0, 0, 0);
}

__device__ __forceinline__ bf16x8 ld8(const u16* p) {
  return *reinterpret_cast<const bf16x8*>(p);
}

// single v_sqrt_f32 (args well-scaled: 1e-6 .. ~300)
__device__ __forceinline__ float fast_sqrt(float x) {
  return __builtin_amdgcn_sqrtf(x);
}

// wave-parallel max over the 64 maxslots (one load + 6-step butterfly)
__device__ __forceinline__ float slots_max(const float* __restrict__ maxslots, int lane) {
  float md = maxslots[lane * 16];
#pragma unroll
  for (int o = 1; o < 64; o <<= 1) md = fmaxf(md, __shfl_xor(md, o));
  return md;
}

// ---------------- prep: sq[i], xb, xT; seed maxslots with LB = max ||x_i - x_0||^2 ----------------
__global__ __launch_bounds__(256) void prep_kernel(const float* __restrict__ x,
                                                   u16* __restrict__ xb, u16* __restrict__ xT,
                                                   float* __restrict__ sq,
                                                   float* __restrict__ maxslots) {
  __shared__ u16 lt[64 * 68];  // [col][row]
  __shared__ float pmax[4];
  const int tid = threadIdx.x, w = tid >> 6, lane = tid & 63;
  const int r0 = blockIdx.x * 64;
  const int rl = tid >> 2;  // local row 0..63
  const int g = tid & 3;    // col quarter (16 cols)
  const int row = r0 + rl;

  const float* xr = x + row * 64 + g * 16;
  const float* x0 = x + g * 16;  // row 0
  float s = 0.f, s2 = 0.f;
  u16 bb[16];
#pragma unroll
  for (int k = 0; k < 4; ++k) {
    float4 v = *reinterpret_cast<const float4*>(xr + k * 4);
    float4 z = *reinterpret_cast<const float4*>(x0 + k * 4);
    s += v.x * v.x + v.y * v.y + v.z * v.z + v.w * v.w;
    float dx = v.x - z.x, dy = v.y - z.y, dz = v.z - z.z, dw = v.w - z.w;
    s2 += dx * dx + dy * dy + dz * dz + dw * dw;
    bb[k * 4 + 0] = f2bf(v.x);
    bb[k * 4 + 1] = f2bf(v.y);
    bb[k * 4 + 2] = f2bf(v.z);
    bb[k * 4 + 3] = f2bf(v.w);
  }
#pragma unroll
  for (int k = 0; k < 4; ++k) {
    u16x4 p;
    p[0] = bb[k * 4]; p[1] = bb[k * 4 + 1]; p[2] = bb[k * 4 + 2]; p[3] = bb[k * 4 + 3];
    *reinterpret_cast<u16x4*>(&xb[row * 64 + g * 16 + k * 4]) = p;
  }
#pragma unroll
  for (int k = 0; k < 16; ++k) lt[(g * 16 + k) * 68 + rl] = bb[k];
  s += __shfl_xor(s, 1);
  s += __shfl_xor(s, 2);
  s2 += __shfl_xor(s2, 1);
  s2 += __shfl_xor(s2, 2);
  if (g == 0) sq[row] = s;
  float wm = s2;
#pragma unroll
  for (int o = 4; o < 64; o <<= 1) wm = fmaxf(wm, __shfl_xor(wm, o));
  if (lane == 0) pmax[w] = wm;
  __syncthreads();
#pragma unroll
  for (int cc = 0; cc < 16; ++cc) {
    int c = w * 16 + cc;
    xT[c * NROW + r0 + lane] = lt[c * 68 + lane];
  }
  if (tid == 0)
    maxslots[blockIdx.x * 16] = fmaxf(fmaxf(pmax[0], pmax[1]), fmaxf(pmax[2], pmax[3]));
}

// ---------------- pass1: exact max d2 (fallback only; early-exits when LB >= rmax^2) ----------------
__global__ __launch_bounds__(256) void pass1_max(const u16* __restrict__ xb,
                                                 const float* __restrict__ sq,
                                                 float* __restrict__ maxslots,
                                                 const float* __restrict__ r0in,
                                                 const float* __restrict__ r1in,
                                                 const float* __restrict__ r2in) {
  __shared__ float red[4];
  int w = threadIdx.x >> 6, lane = threadIdx.x & 63;
  {
    float lb = slots_max(maxslots, lane);
    float rmax = fmaxf(fmaxf(r0in[0], r1in[0]), r2in[0]);
    if (lb >= rmax * rmax) return;  // uniform across grid; min(r, max_dist) == r exactly
  }
  int l16 = lane & 15, quad = lane >> 4;
  int ti = blockIdx.x;
  int i0 = ti * 64 + w * 16;
  bf16x8 a0 = ld8(xb + (i0 + l16) * 64 + quad * 8);
  bf16x8 a1 = ld8(xb + (i0 + l16) * 64 + 32 + quad * 8);
  float sqi[4];
#pragma unroll
  for (int r = 0; r < 4; ++r) sqi[r] = sq[i0 + quad * 4 + r];
  float m = 0.f;
  const int jbase = blockIdx.y * 256;
#pragma unroll
  for (int jb = 0; jb < 4; ++jb) {
    int j0 = jbase + jb * 64;
#pragma unroll
    for (int jt = 0; jt < 4; ++jt) {
      int jr = j0 + jt * 16 + l16;
      bf16x8 b0 = ld8(xb + jr * 64 + quad * 8);
      bf16x8 b1 = ld8(xb + jr * 64 + 32 + quad * 8);
      f32x4 g = {0.f, 0.f, 0.f, 0.f};
      g = mfma16(a0, b0, g);
      g = mfma16(a1, b1, g);
      float sj = sq[jr];
#pragma unroll
      for (int r = 0; r < 4; ++r) m = fmaxf(m, fmaf(-2.f, g[r], sqi[r] + sj));
    }
  }
  m = fmaxf(m, 0.f);
#pragma unroll
  for (int o = 1; o < 64; o <<= 1) m = fmaxf(m, __shfl_xor(m, o));
  if (lane == 0) red[w] = m;
  __syncthreads();
  if (threadIdx.x == 0) {
    m = fmaxf(fmaxf(red[0], red[1]), fmaxf(red[2], red[3]));
    atomicMax((int*)&maxslots[ti * 16], __float_as_int(m));
  }
}

// ---------------- pass2: alpha weights + mu partials, barrier-free chained-MFMA ----------------
// 4-round redbuf (16 j each) keeps LDS at 27.6 KB -> 4 blocks/CU with
// launch_bounds(256,4) when NS=16 gives a 1024-block grid (4 waves/SIMD TLP).
template <int NS>
__global__ __launch_bounds__(256, 4) void pass2_kernel(
    const u16* __restrict__ xb, const u16* __restrict__ xT, const float* __restrict__ sq,
    const float* __restrict__ maxslots, const float* __restrict__ r0in,
    float* __restrict__ mu_part, float* __restrict__ s_part) {
  constexpr int SPAN = NROW / NS;
  constexpr int STEPS = SPAN / 64;
  __shared__ u16 xjt[64 * LDW];          // 9.2 KB
  __shared__ float redbuf[4][16 * RDW];  // 17.4 KB
  __shared__ float sred[4][64];
  const int tid = threadIdx.x, w = tid >> 6, lane = tid & 63;
  const int l16 = lane & 15, quad = lane >> 4;
  const int j0 = blockIdx.x * 64;
  const int ibase = blockIdx.y * SPAN;

#pragma unroll
  for (int k = 0; k < 2; ++k) {
    int ch = tid + k * 256;
    int row = ch >> 3, c8 = ch & 7;
    *reinterpret_cast<bf16x8*>(&xjt[row * LDW + c8 * 8]) = ld8(xb + (j0 + row) * 64 + c8 * 8);
  }

  const float md = slots_max(maxslots, lane);
  const float r0c = fminf(r0in[0], fast_sqrt(md));
  const float invr0sq = 1.f / (r0c * r0c);

  float sqj[4];
#pragma unroll
  for (int jt = 0; jt < 4; ++jt) sqj[jt] = sq[j0 + jt * 16 + l16];

  f32x4 zero4 = {0.f, 0.f, 0.f, 0.f};
  f32x4 acc[4][4];  // [jt][pt]; j = jt*16+quad*4+r, p = pt*16+l16
#pragma unroll
  for (int jt = 0; jt < 4; ++jt)
#pragma unroll
    for (int pt = 0; pt < 4; ++pt) acc[jt][pt] = zero4;
  float sa[4] = {0.f, 0.f, 0.f, 0.f};

  const int iw0 = ibase + w * 16;
  bf16x8 a0 = ld8(xb + (iw0 + l16) * 64 + quad * 8);
  bf16x8 a1 = ld8(xb + (iw0 + l16) * 64 + 32 + quad * 8);
  float4 qi = *reinterpret_cast<const float4*>(&sq[iw0 + quad * 4]);
  __syncthreads();  // xjt ready (only barrier before block-end)

#pragma unroll
  for (int s = 0; s < STEPS; ++s) {
    const int ib_w = ibase + s * 64 + w * 16;
    bf16x8 na0, na1;
    float4 nqi;
    if (s < STEPS - 1) {
      const int irn = ibase + (s + 1) * 64 + w * 16;
      na0 = ld8(xb + (irn + l16) * 64 + quad * 8);
      na1 = ld8(xb + (irn + l16) * 64 + 32 + quad * 8);
      nqi = *reinterpret_cast<const float4*>(&sq[irn + quad * 4]);
    }
    s16x4 bfr[4];
#pragma unroll
    for (int pt = 0; pt < 4; ++pt)
      bfr[pt] =
          *reinterpret_cast<const s16x4*>(xT + (pt * 16 + l16) * NROW + ib_w + quad * 4);
#pragma unroll
    for (int jt = 0; jt < 4; ++jt) {
      bf16x8 xj0 = ld8(&xjt[(jt * 16 + l16) * LDW + quad * 8]);
      bf16x8 xj1 = ld8(&xjt[(jt * 16 + l16) * LDW + 32 + quad * 8]);
      f32x4 g = zero4;
      g = mfma16(a0, xj0, g);
      g = mfma16(a1, xj1, g);
      s16x4 wf;
#pragma unroll
      for (int r = 0; r < 4; ++r) {
        float d2 = fmaxf(fmaf(-2.f, g[r], qi[r] + sqj[jt]), 0.f);
        float ba = fmaxf(fmaf(-d2, invr0sq, 1.f), 0.f);
        float wv = ba * ba * ba;
        sa[jt] += wv;
        wf[r] = (short)f2bf_t(wv);
      }
#pragma unroll
      for (int pt = 0; pt < 4; ++pt) acc[jt][pt] = mfma16k(wf, bfr[pt], acc[jt][pt]);
    }
    if (s < STEPS - 1) {
      a0 = na0;
      a1 = na1;
      qi = nqi;
    }
  }

  // block-end: cross-wave reduce of acc via LDS, 4 rounds of 16 j
  float* mp = mu_part + (size_t)blockIdx.y * SLICE;
#pragma unroll
  for (int rd = 0; rd < 4; ++rd) {
    __syncthreads();  // protect redbuf vs previous round's reads
#pragma unroll
    for (int pt = 0; pt < 4; ++pt)
#pragma unroll
      for (int r = 0; r < 4; ++r)
        redbuf[w][(quad * 4 + r) * RDW + pt * 16 + l16] = acc[rd][pt][r];
    __syncthreads();
#pragma unroll
    for (int jj = 0; jj < 4; ++jj) {
      const int jrel = w * 4 + jj;
      float v = redbuf[0][jrel * RDW + lane] + redbuf[1][jrel * RDW + lane] +
                redbuf[2][jrel * RDW + lane] + redbuf[3][jrel * RDW + lane];
      mp[(j0 + rd * 16 + jrel) * 64 + lane] = v;
    }
  }
#pragma unroll
  for (int jt = 0; jt < 4; ++jt) {
    float v = sa[jt];
    v += __shfl_xor(v, 16);
    v += __shfl_xor(v, 32);
    if (lane < 16) sred[w][jt * 16 + lane] = v;
  }
  __syncthreads();
  if (tid < 64)
    s_part[blockIdx.y * NROW + j0 + tid] =
        sred[0][tid] + sred[1][tid] + sred[2][tid] + sred[3][tid];
}

// ---------------- pass3: merged finish_mu + beta weights + e_Z partials ----------------
template <int NS>
__global__ __launch_bounds__(256, 4) void pass3_kernel(
    const u16* __restrict__ xb, const u16* __restrict__ xT, const float* __restrict__ sq,
    const float* __restrict__ mu_part, const float* __restrict__ s_part_a,
    const float* __restrict__ maxslots, const float* __restrict__ r1in,
    const float* __restrict__ r2in, const float* __restrict__ x,
    float* __restrict__ ez_part, float* __restrict__ s_part) {
  constexpr int SPAN = NROW / NS;
  constexpr int STEPS = SPAN / 64;
  __shared__ u16 xjt[64 * LDW];
  __shared__ u16 ujt[64 * LDW];
  __shared__ float redbuf[4][16 * RDW];
  __shared__ float sred[4][64];
  __shared__ float tj_s[64], u2_s[64];
  const int tid = threadIdx.x, w = tid >> 6, lane = tid & 63;
  const int l16 = lane & 15, quad = lane >> 4;
  const int j0 = blockIdx.x * 64;
  const int ibase = blockIdx.y * SPAN;

#pragma unroll
  for (int k = 0; k < 2; ++k) {
    int ch = tid + k * 256;
    int row = ch >> 3, c8 = ch & 7;
    *reinterpret_cast<bf16x8*>(&xjt[row * LDW + c8 * 8]) = ld8(xb + (j0 + row) * 64 + c8 * 8);
  }

  // merged finish_mu for this block's 64 j-rows (stream-ordered after pass2)
  {
    const int rl16 = tid >> 4;
    const int c4 = tid & 15;
#pragma unroll
    for (int sw = 0; sw < 4; ++sw) {
      const int lrow = sw * 16 + rl16;
      const int row = j0 + lrow;
      float4 num = {0.f, 0.f, 0.f, 0.f};
      float den = 0.f;
#pragma unroll
      for (int y = 0; y < NS; ++y) {
        float4 v =
            *reinterpret_cast<const float4*>(&mu_part[(size_t)y * SLICE + row * 64 + c4 * 4]);
        num.x += v.x; num.y += v.y; num.z += v.z; num.w += v.w;
        den += s_part_a[y * NROW + row];
      }
      float4 xv = *reinterpret_cast<const float4*>(&x[row * 64 + c4 * 4]);
      float inv = 1.f / den;
      float m0 = num.x * inv, m1 = num.y * inv, m2 = num.z * inv, m3 = num.w * inv;
      if (m0 != m0) m0 = xv.x;
      if (m1 != m1) m1 = xv.y;
      if (m2 != m2) m2 = xv.z;
      if (m3 != m3) m3 = xv.w;
      float U0 = xv.x - m0, U1 = xv.y - m1, U2 = xv.z - m2, U3 = xv.w - m3;
      u16x4 pb;
      pb[0] = f2bf(U0); pb[1] = f2bf(U1); pb[2] = f2bf(U2); pb[3] = f2bf(U3);
      *reinterpret_cast<u16x4*>(&ujt[lrow * LDW + c4 * 4]) = pb;
      float aa = U0 * U0 + U1 * U1 + U2 * U2 + U3 * U3;
      float bb = xv.x * U0 + xv.y * U1 + xv.z * U2 + xv.w * U3;
#pragma unroll
      for (int o = 1; o < 16; o <<= 1) {
        aa += __shfl_xor(aa, o);
        bb += __shfl_xor(bb, o);
      }
      if (c4 == 0) {
        u2_s[lrow] = aa;
        tj_s[lrow] = bb;
      }
    }
  }

  const float md = slots_max(maxslots, lane);
  const float mdist = fast_sqrt(md);
  const float r1c = fminf(r1in[0], mdist);
  const float r2c = fminf(r2in[0], mdist);
  const float i1x2 = 2.f / r1c;
  const float i2x2 = 2.f / r2c;

  f32x4 zero4 = {0.f, 0.f, 0.f, 0.f};
  f32x4 acc[4][4];
#pragma unroll
  for (int jt = 0; jt < 4; ++jt)
#pragma unroll
    for (int pt = 0; pt < 4; ++pt) acc[jt][pt] = zero4;
  float sb[4] = {0.f, 0.f, 0.f, 0.f};

  const int iw0 = ibase + w * 16;
  bf16x8 a0 = ld8(xb + (iw0 + l16) * 64 + quad * 8);
  bf16x8 a1 = ld8(xb + (iw0 + l16) * 64 + 32 + quad * 8);
  float4 qi = *reinterpret_cast<const float4*>(&sq[iw0 + quad * 4]);
  __syncthreads();  // xjt, ujt, tj_s/u2_s ready

  float sqj[4], tj[4], u2j[4];
#pragma unroll
  for (int jt = 0; jt < 4; ++jt) {
    sqj[jt] = sq[j0 + jt * 16 + l16];
    tj[jt] = tj_s[jt * 16 + l16];
    u2j[jt] = u2_s[jt * 16 + l16];
  }

#pragma unroll
  for (int s = 0; s < STEPS; ++s) {
    const int ib_w = ibase + s * 64 + w * 16;
    bf16x8 na0, na1;
    float4 nqi;
    if (s < STEPS - 1) {
      const int irn = ibase + (s + 1) * 64 + w * 16;
      na0 = ld8(xb + (irn + l16) * 64 + quad * 8);
      na1 = ld8(xb + (irn + l16) * 64 + 32 + quad * 8);
      nqi = *reinterpret_cast<const float4*>(&sq[irn + quad * 4]);
    }
    s16x4 bfr[4];
#pragma unroll
    for (int pt = 0; pt < 4; ++pt)
      bfr[pt] =
          *reinterpret_cast<const s16x4*>(xT + (pt * 16 + l16) * NROW + ib_w + quad * 4);
#pragma unroll
    for (int jt = 0; jt < 4; ++jt) {
      bf16x8 xf0 = ld8(&xjt[(jt * 16 + l16) * LDW + quad * 8]);
      bf16x8 uf0 = ld8(&ujt[(jt * 16 + l16) * LDW + quad * 8]);
      bf16x8 xf1 = ld8(&xjt[(jt * 16 + l16) * LDW + 32 + quad * 8]);
      bf16x8 uf1 = ld8(&ujt[(jt * 16 + l16) * LDW + 32 + quad * 8]);
      f32x4 gxx = zero4, gxu = zero4;
      gxx = mfma16(a0, xf0, gxx);
      gxu = mfma16(a0, uf0, gxu);
      gxx = mfma16(a1, xf1, gxx);
      gxu = mfma16(a1, uf1, gxu);
      const float tjv = tj[jt], u2jv = u2j[jt], sjv = sqj[jt];
      s16x4 wf;
#pragma unroll
      for (int r = 0; r < 4; ++r) {
        float d2 = fmaxf(fmaf(-2.f, gxx[r], qi[r] + sjv), 0.f);
        float c = gxu[r] - tjv;
        float du2 = fmaxf(c * c * u2jv, 1e-6f);
        float dv2 = fmaxf(d2 - du2, 1e-6f);
        float du = fast_sqrt(du2);
        float dv = fast_sqrt(dv2);
        // w(d) = (1 - t^2)^3, t = clamp(2d/r - 1, 0, 1): exact on all 3 branches
        float q1 = fminf(fmaxf(fmaf(dv, i1x2, -1.f), 0.f), 1.f);
        float b1 = fmaf(-q1, q1, 1.f);
        float w1 = b1 * b1 * b1;
        float q2 = fminf(fmaxf(fmaf(du, i2x2, -1.f), 0.f), 1.f);
        float b2 = fmaf(-q2, q2, 1.f);
        float w2 = b2 * b2 * b2;
        float wv = w1 * w2;
        sb[jt] += wv;
        wf[r] = (short)f2bf_t(wv);
      }
#pragma unroll
      for (int pt = 0; pt < 4; ++pt) acc[jt][pt] = mfma16k(wf, bfr[pt], acc[jt][pt]);
    }
    if (s < STEPS - 1) {
      a0 = na0;
      a1 = na1;
      qi = nqi;
    }
  }

  float* ep = ez_part + (size_t)blockIdx.y * SLICE;
#pragma unroll
  for (int rd = 0; rd < 4; ++rd) {
    __syncthreads();
#pragma unroll
    for (int pt = 0; pt < 4; ++pt)
#pragma unroll
      for (int r = 0; r < 4; ++r)
        redbuf[w][(quad * 4 + r) * RDW + pt * 16 + l16] = acc[rd][pt][r];
    __syncthreads();
#pragma unroll
    for (int jj = 0; jj < 4; ++jj) {
      const int jrel = w * 4 + jj;
      float v = redbuf[0][jrel * RDW + lane] + redbuf[1][jrel * RDW + lane] +
                redbuf[2][jrel * RDW + lane] + redbuf[3][jrel * RDW + lane];
      ep[(j0 + rd * 16 + jrel) * 64 + lane] = v;
    }
  }
#pragma unroll
  for (int jt = 0; jt < 4; ++jt) {
    float v = sb[jt];
    v += __shfl_xor(v, 16);
    v += __shfl_xor(v, 32);
    if (lane < 16) sred[w][jt * 16 + lane] = v;
  }
  __syncthreads();
  if (tid < 64)
    s_part[blockIdx.y * NROW + j0 + tid] =
        sred[0][tid] + sred[1][tid] + sred[2][tid] + sred[3][tid];
}

// ---------------- finish: float4 reduce partials, NaN -> x ----------------
template <int NS>
__global__ __launch_bounds__(256) void finish_kernel(const float* __restrict__ x,
                                                     const float* __restrict__ ez_part,
                                                     const float* __restrict__ s_part,
                                                     float* __restrict__ out) {
  const int tid = threadIdx.x;
  const int row = blockIdx.x * 16 + (tid >> 4);
  const int c4 = tid & 15;
  float4 num = {0.f, 0.f, 0.f, 0.f};
  float den = 0.f;
#pragma unroll
  for (int y = 0; y < NS; ++y) {
    float4 v = *reinterpret_cast<const float4*>(&ez_part[(size_t)y * SLICE + row * 64 + c4 * 4]);
    num.x += v.x; num.y += v.y; num.z += v.z; num.w += v.w;
    den += s_part[y * NROW + row];
  }
  float4 xv = *reinterpret_cast<const float4*>(&x[row * 64 + c4 * 4]);
  float inv = 1.f / den;
  float4 o;
  o.x = num.x * inv; o.y = num.y * inv; o.z = num.z * inv; o.w = num.w * inv;
  if (o.x != o.x) o.x = xv.x;
  if (o.y != o.y) o.y = xv.y;
  if (o.z != o.z) o.z = xv.z;
  if (o.w != o.w) o.w = xv.w;
  *reinterpret_cast<float4*>(&out[row * 64 + c4 * 4]) = o;
}

extern "C" void kernel_launch(void* const* d_in, const int* in_sizes, int n_in,
                              void* d_out, int out_size, void* d_ws, size_t ws_size,
                              hipStream_t stream) {
  (void)in_sizes; (void)n_in; (void)out_size;
  const float* x = (const float*)d_in[0];
  const float* r0 = (const float*)d_in[1];
  const float* r1 = (const float*)d_in[2];
  const float* r2 = (const float*)d_in[3];
  float* out = (float*)d_out;
  char* ws = (char*)d_ws;

  u16* xb = (u16*)(ws);                              // 512 KB
  u16* xT = (u16*)(ws + (512 << 10));                // 512 KB
  float* sq = (float*)(ws + (1536 << 10));           // 16 KB
  float* maxslots = (float*)(ws + (1584 << 10));     // 4 KB
  float* s_part_a = (float*)(ws + (1588 << 10));     // 256 KB
  float* s_part_b = (float*)(ws + (1844 << 10));     // 256 KB
  const size_t base = (size_t)2100 << 10;
  float* part_mu = (float*)(ws + base);

  const size_t need16 = base + ((size_t)32 << 20);  // 16 MB mu + 16 MB ez
  const size_t need8 = base + ((size_t)16 << 20);   // 8 MB mu + 8 MB ez

  prep_kernel<<<64, 256, 0, stream>>>(x, xb, xT, sq, maxslots);
  pass1_max<<<dim3(64, 16), 256, 0, stream>>>(xb, sq, maxslots, r0, r1, r2);

  if (ws_size >= need16) {
    // NS=16: 1024 blocks = 4 blocks/CU = 4 waves/SIMD (double TLP)
    float* part_ez = (float*)(ws + base + ((size_t)16 << 20));
    pass2_kernel<16><<<dim3(64, 16), 256, 0, stream>>>(xb, xT, sq, maxslots, r0, part_mu,
                                                       s_part_a);
    pass3_kernel<16><<<dim3(64, 16), 256, 0, stream>>>(xb, xT, sq, part_mu, s_part_a,
                                                       maxslots, r1, r2, x, part_ez,
                                                       s_part_b);
    finish_kernel<16><<<256, 256, 0, stream>>>(x, part_ez, s_part_b, out);
  } else if (ws_size >= need8) {
    // fallback: proven NS=8 path (R11 behavior)
    float* part_ez = (float*)(ws + base + ((size_t)8 << 20));
    pass2_kernel<8><<<dim3(64, 8), 256, 0, stream>>>(xb, xT, sq, maxslots, r0, part_mu,
                                                     s_part_a);
    pass3_kernel<8><<<dim3(64, 8), 256, 0, stream>>>(xb, xT, sq, part_mu, s_part_a, maxslots,
                                                     r1, r2, x, part_ez, s_part_b);
    finish_kernel<8><<<256, 256, 0, stream>>>(x, part_ez, s_part_b, out);
  }
}

// Round 13
// 114.152 us; speedup vs baseline: 1.5847x; 1.5847x over previous
//
#include <hip/hip_runtime.h>
#include <stdint.h>

typedef unsigned short u16;
typedef short bf16x8 __attribute__((ext_vector_type(8)));
typedef short s16x4 __attribute__((ext_vector_type(4)));
typedef unsigned short u16x4 __attribute__((ext_vector_type(4)));
typedef float f32x4 __attribute__((ext_vector_type(4)));

#define NROW 4096
#define LDW 72  // LDS row stride (u16) for 64x64 tiles (stride-72: 2-way max, free)
#define RDW 68  // redbuf row stride (f32): breaks quad-stride bank aliasing
#define SLICE 262144  // 4096*64 floats per partial slice
#define NSPLIT 8      // split-k over i: 512 blocks = 2 blocks/CU (proven sweet spot)

// round-to-nearest-even float -> bf16 bits (x, U: fidelity matters)
__device__ __forceinline__ u16 f2bf(float f) {
  uint32_t u = __float_as_uint(f);
  u = (u + 0x7fffu + ((u >> 16) & 1u)) >> 16;
  return (u16)u;
}

// truncating float -> bf16 (weights only: bias cancels between num and den)
__device__ __forceinline__ u16 f2bf_t(float f) {
  return (u16)(__float_as_uint(f) >> 16);
}

__device__ __forceinline__ f32x4 mfma16(bf16x8 a, bf16x8 b, f32x4 c) {
  return __builtin_amdgcn_mfma_f32_16x16x32_bf16(a, b, c, 0, 0, 0);
}

// chained second-GEMM MFMA: the 16x16x32 C-fragment (row=quad*4+r, col=l16) is
// exactly the 16x16x16 A-operand layout (row=lane&15, k=(lane>>4)*4+reg), so the
// weight fragment feeds this with NO LDS transpose.
__device__ __forceinline__ f32x4 mfma16k(s16x4 a, s16x4 b, f32x4 c) {
  return __builtin_amdgcn_mfma_f32_16x16x16bf16_1k(a, b, c, 0, 0, 0);
}

__device__ __forceinline__ bf16x8 ld8(const u16* p) {
  return *reinterpret_cast<const bf16x8*>(p);
}

// single v_sqrt_f32 (args well-scaled: 1e-6 .. ~300)
__device__ __forceinline__ float fast_sqrt(float x) {
  return __builtin_amdgcn_sqrtf(x);
}

// wave-parallel max over the 64 maxslots (one load + 6-step butterfly)
__device__ __forceinline__ float slots_max(const float* __restrict__ maxslots, int lane) {
  float md = maxslots[lane * 16];
#pragma unroll
  for (int o = 1; o < 64; o <<= 1) md = fmaxf(md, __shfl_xor(md, o));
  return md;
}

// ---------------- prep: sq[i], xb, xT; seed maxslots with LB = max ||x_i - x_0||^2 ----------------
__global__ __launch_bounds__(256) void prep_kernel(const float* __restrict__ x,
                                                   u16* __restrict__ xb, u16* __restrict__ xT,
                                                   float* __restrict__ sq,
                                                   float* __restrict__ maxslots) {
  __shared__ u16 lt[64 * 68];  // [col][row]
  __shared__ float pmax[4];
  const int tid = threadIdx.x, w = tid >> 6, lane = tid & 63;
  const int r0 = blockIdx.x * 64;
  const int rl = tid >> 2;  // local row 0..63
  const int g = tid & 3;    // col quarter (16 cols)
  const int row = r0 + rl;

  const float* xr = x + row * 64 + g * 16;
  const float* x0 = x + g * 16;  // row 0
  float s = 0.f, s2 = 0.f;
  u16 bb[16];
#pragma unroll
  for (int k = 0; k < 4; ++k) {
    float4 v = *reinterpret_cast<const float4*>(xr + k * 4);
    float4 z = *reinterpret_cast<const float4*>(x0 + k * 4);
    s += v.x * v.x + v.y * v.y + v.z * v.z + v.w * v.w;
    float dx = v.x - z.x, dy = v.y - z.y, dz = v.z - z.z, dw = v.w - z.w;
    s2 += dx * dx + dy * dy + dz * dz + dw * dw;
    bb[k * 4 + 0] = f2bf(v.x);
    bb[k * 4 + 1] = f2bf(v.y);
    bb[k * 4 + 2] = f2bf(v.z);
    bb[k * 4 + 3] = f2bf(v.w);
  }
#pragma unroll
  for (int k = 0; k < 4; ++k) {
    u16x4 p;
    p[0] = bb[k * 4]; p[1] = bb[k * 4 + 1]; p[2] = bb[k * 4 + 2]; p[3] = bb[k * 4 + 3];
    *reinterpret_cast<u16x4*>(&xb[row * 64 + g * 16 + k * 4]) = p;
  }
#pragma unroll
  for (int k = 0; k < 16; ++k) lt[(g * 16 + k) * 68 + rl] = bb[k];
  s += __shfl_xor(s, 1);
  s += __shfl_xor(s, 2);
  s2 += __shfl_xor(s2, 1);
  s2 += __shfl_xor(s2, 2);
  if (g == 0) sq[row] = s;
  float wm = s2;
#pragma unroll
  for (int o = 4; o < 64; o <<= 1) wm = fmaxf(wm, __shfl_xor(wm, o));
  if (lane == 0) pmax[w] = wm;
  __syncthreads();
#pragma unroll
  for (int cc = 0; cc < 16; ++cc) {
    int c = w * 16 + cc;
    xT[c * NROW + r0 + lane] = lt[c * 68 + lane];
  }
  if (tid == 0)
    maxslots[blockIdx.x * 16] = fmaxf(fmaxf(pmax[0], pmax[1]), fmaxf(pmax[2], pmax[3]));
}

// ---------------- pass1: exact max d2 (fallback only; early-exits when LB >= rmax^2) ----------------
__global__ __launch_bounds__(256) void pass1_max(const u16* __restrict__ xb,
                                                 const float* __restrict__ sq,
                                                 float* __restrict__ maxslots,
                                                 const float* __restrict__ r0in,
                                                 const float* __restrict__ r1in,
                                                 const float* __restrict__ r2in) {
  __shared__ float red[4];
  int w = threadIdx.x >> 6, lane = threadIdx.x & 63;
  {
    float lb = slots_max(maxslots, lane);
    float rmax = fmaxf(fmaxf(r0in[0], r1in[0]), r2in[0]);
    if (lb >= rmax * rmax) return;  // uniform across grid; min(r, max_dist) == r exactly
  }
  int l16 = lane & 15, quad = lane >> 4;
  int ti = blockIdx.x;
  int i0 = ti * 64 + w * 16;
  bf16x8 a0 = ld8(xb + (i0 + l16) * 64 + quad * 8);
  bf16x8 a1 = ld8(xb + (i0 + l16) * 64 + 32 + quad * 8);
  float sqi[4];
#pragma unroll
  for (int r = 0; r < 4; ++r) sqi[r] = sq[i0 + quad * 4 + r];
  float m = 0.f;
  const int jbase = blockIdx.y * 256;
#pragma unroll
  for (int jb = 0; jb < 4; ++jb) {
    int j0 = jbase + jb * 64;
#pragma unroll
    for (int jt = 0; jt < 4; ++jt) {
      int jr = j0 + jt * 16 + l16;
      bf16x8 b0 = ld8(xb + jr * 64 + quad * 8);
      bf16x8 b1 = ld8(xb + jr * 64 + 32 + quad * 8);
      f32x4 g = {0.f, 0.f, 0.f, 0.f};
      g = mfma16(a0, b0, g);
      g = mfma16(a1, b1, g);
      float sj = sq[jr];
#pragma unroll
      for (int r = 0; r < 4; ++r) m = fmaxf(m, fmaf(-2.f, g[r], sqi[r] + sj));
    }
  }
  m = fmaxf(m, 0.f);
#pragma unroll
  for (int o = 1; o < 64; o <<= 1) m = fmaxf(m, __shfl_xor(m, o));
  if (lane == 0) red[w] = m;
  __syncthreads();
  if (threadIdx.x == 0) {
    m = fmaxf(fmaxf(red[0], red[1]), fmaxf(red[2], red[3]));
    atomicMax((int*)&maxslots[ti * 16], __float_as_int(m));
  }
}

// ---------------- pass2: alpha weights + mu partials, BARRIER-FREE K-loop ----------------
// R11 structure (proven 114.4us) + depth-1 rolling prefetch extended to the xT
// bfr fragments (the one chain load not previously prefetched). (256,2): the
// working set needs 128+ VGPR/wave; tighter bounds spill (R12: VGPR 64, +180MB
// scratch).
__global__ __launch_bounds__(256, 2) void pass2_kernel(
    const u16* __restrict__ xb, const u16* __restrict__ xT, const float* __restrict__ sq,
    const float* __restrict__ maxslots, const float* __restrict__ r0in,
    float* __restrict__ mu_part, float* __restrict__ s_part) {
  __shared__ u16 xjt[64 * LDW];          // 9.2 KB
  __shared__ float redbuf[4][32 * RDW];  // 34.8 KB
  __shared__ float sred[4][64];
  const int tid = threadIdx.x, w = tid >> 6, lane = tid & 63;
  const int l16 = lane & 15, quad = lane >> 4;
  const int j0 = blockIdx.x * 64;
  const int ibase = blockIdx.y * 512;

#pragma unroll
  for (int k = 0; k < 2; ++k) {
    int ch = tid + k * 256;
    int row = ch >> 3, c8 = ch & 7;
    *reinterpret_cast<bf16x8*>(&xjt[row * LDW + c8 * 8]) = ld8(xb + (j0 + row) * 64 + c8 * 8);
  }

  const float md = slots_max(maxslots, lane);
  const float r0c = fminf(r0in[0], fast_sqrt(md));
  const float invr0sq = 1.f / (r0c * r0c);

  float sqj[4];
#pragma unroll
  for (int jt = 0; jt < 4; ++jt) sqj[jt] = sq[j0 + jt * 16 + l16];

  f32x4 zero4 = {0.f, 0.f, 0.f, 0.f};
  f32x4 acc[4][4];  // [jt][pt]; j = jt*16+quad*4+r, p = pt*16+l16
#pragma unroll
  for (int jt = 0; jt < 4; ++jt)
#pragma unroll
    for (int pt = 0; pt < 4; ++pt) acc[jt][pt] = zero4;
  float sa[4] = {0.f, 0.f, 0.f, 0.f};

  const int iw0 = ibase + w * 16;
  bf16x8 a0 = ld8(xb + (iw0 + l16) * 64 + quad * 8);
  bf16x8 a1 = ld8(xb + (iw0 + l16) * 64 + 32 + quad * 8);
  float4 qi = *reinterpret_cast<const float4*>(&sq[iw0 + quad * 4]);
  s16x4 bfr[4];
#pragma unroll
  for (int pt = 0; pt < 4; ++pt)
    bfr[pt] = *reinterpret_cast<const s16x4*>(xT + (pt * 16 + l16) * NROW + iw0 + quad * 4);
  __syncthreads();  // xjt ready (only barrier before block-end)

#pragma unroll
  for (int s = 0; s < 8; ++s) {
    bf16x8 na0, na1;
    float4 nqi;
    s16x4 nbfr[4];
    if (s < 7) {
      const int irn = ibase + (s + 1) * 64 + w * 16;
      na0 = ld8(xb + (irn + l16) * 64 + quad * 8);
      na1 = ld8(xb + (irn + l16) * 64 + 32 + quad * 8);
      nqi = *reinterpret_cast<const float4*>(&sq[irn + quad * 4]);
#pragma unroll
      for (int pt = 0; pt < 4; ++pt)
        nbfr[pt] =
            *reinterpret_cast<const s16x4*>(xT + (pt * 16 + l16) * NROW + irn + quad * 4);
    }
#pragma unroll
    for (int jt = 0; jt < 4; ++jt) {
      bf16x8 xj0 = ld8(&xjt[(jt * 16 + l16) * LDW + quad * 8]);
      bf16x8 xj1 = ld8(&xjt[(jt * 16 + l16) * LDW + 32 + quad * 8]);
      f32x4 g = zero4;
      g = mfma16(a0, xj0, g);
      g = mfma16(a1, xj1, g);
      s16x4 wf;
#pragma unroll
      for (int r = 0; r < 4; ++r) {
        float d2 = fmaxf(fmaf(-2.f, g[r], qi[r] + sqj[jt]), 0.f);
        float ba = fmaxf(fmaf(-d2, invr0sq, 1.f), 0.f);
        float wv = ba * ba * ba;
        sa[jt] += wv;
        wf[r] = (short)f2bf_t(wv);
      }
#pragma unroll
      for (int pt = 0; pt < 4; ++pt) acc[jt][pt] = mfma16k(wf, bfr[pt], acc[jt][pt]);
    }
    if (s < 7) {
      a0 = na0;
      a1 = na1;
      qi = nqi;
#pragma unroll
      for (int pt = 0; pt < 4; ++pt) bfr[pt] = nbfr[pt];
    }
  }

  // block-end: cross-wave reduce of acc via LDS, 2 rounds of 32 j
  float* mp = mu_part + (size_t)blockIdx.y * SLICE;
#pragma unroll
  for (int rd = 0; rd < 2; ++rd) {
    __syncthreads();  // protect redbuf vs previous round's reads
#pragma unroll
    for (int jh = 0; jh < 2; ++jh) {
      const int jt = rd * 2 + jh;
#pragma unroll
      for (int pt = 0; pt < 4; ++pt)
#pragma unroll
        for (int r = 0; r < 4; ++r)
          redbuf[w][(jh * 16 + quad * 4 + r) * RDW + pt * 16 + l16] = acc[jt][pt][r];
    }
    __syncthreads();
#pragma unroll
    for (int jj = 0; jj < 8; ++jj) {
      const int jrel = w * 8 + jj;
      float v = redbuf[0][jrel * RDW + lane] + redbuf[1][jrel * RDW + lane] +
                redbuf[2][jrel * RDW + lane] + redbuf[3][jrel * RDW + lane];
      mp[(j0 + rd * 32 + jrel) * 64 + lane] = v;
    }
  }
#pragma unroll
  for (int jt = 0; jt < 4; ++jt) {
    float v = sa[jt];
    v += __shfl_xor(v, 16);
    v += __shfl_xor(v, 32);
    if (lane < 16) sred[w][jt * 16 + lane] = v;
  }
  __syncthreads();
  if (tid < 64)
    s_part[blockIdx.y * NROW + j0 + tid] =
        sred[0][tid] + sred[1][tid] + sred[2][tid] + sred[3][tid];
}

// ---------------- pass3: merged finish_mu + beta weights + e_Z partials ----------------
__global__ __launch_bounds__(256, 2) void pass3_kernel(
    const u16* __restrict__ xb, const u16* __restrict__ xT, const float* __restrict__ sq,
    const float* __restrict__ mu_part, const float* __restrict__ s_part_a,
    const float* __restrict__ maxslots, const float* __restrict__ r1in,
    const float* __restrict__ r2in, const float* __restrict__ x,
    float* __restrict__ ez_part, float* __restrict__ s_part) {
  __shared__ u16 xjt[64 * LDW];
  __shared__ u16 ujt[64 * LDW];
  __shared__ float redbuf[4][32 * RDW];
  __shared__ float sred[4][64];
  __shared__ float tj_s[64], u2_s[64];
  const int tid = threadIdx.x, w = tid >> 6, lane = tid & 63;
  const int l16 = lane & 15, quad = lane >> 4;
  const int j0 = blockIdx.x * 64;
  const int ibase = blockIdx.y * 512;

#pragma unroll
  for (int k = 0; k < 2; ++k) {
    int ch = tid + k * 256;
    int row = ch >> 3, c8 = ch & 7;
    *reinterpret_cast<bf16x8*>(&xjt[row * LDW + c8 * 8]) = ld8(xb + (j0 + row) * 64 + c8 * 8);
  }

  // merged finish_mu for this block's 64 j-rows (stream-ordered after pass2)
  {
    const int rl16 = tid >> 4;
    const int c4 = tid & 15;
#pragma unroll
    for (int sw = 0; sw < 4; ++sw) {
      const int lrow = sw * 16 + rl16;
      const int row = j0 + lrow;
      float4 num = {0.f, 0.f, 0.f, 0.f};
      float den = 0.f;
#pragma unroll
      for (int y = 0; y < NSPLIT; ++y) {
        float4 v =
            *reinterpret_cast<const float4*>(&mu_part[(size_t)y * SLICE + row * 64 + c4 * 4]);
        num.x += v.x; num.y += v.y; num.z += v.z; num.w += v.w;
        den += s_part_a[y * NROW + row];
      }
      float4 xv = *reinterpret_cast<const float4*>(&x[row * 64 + c4 * 4]);
      float inv = 1.f / den;
      float m0 = num.x * inv, m1 = num.y * inv, m2 = num.z * inv, m3 = num.w * inv;
      if (m0 != m0) m0 = xv.x;
      if (m1 != m1) m1 = xv.y;
      if (m2 != m2) m2 = xv.z;
      if (m3 != m3) m3 = xv.w;
      float U0 = xv.x - m0, U1 = xv.y - m1, U2 = xv.z - m2, U3 = xv.w - m3;
      u16x4 pb;
      pb[0] = f2bf(U0); pb[1] = f2bf(U1); pb[2] = f2bf(U2); pb[3] = f2bf(U3);
      *reinterpret_cast<u16x4*>(&ujt[lrow * LDW + c4 * 4]) = pb;
      float aa = U0 * U0 + U1 * U1 + U2 * U2 + U3 * U3;
      float bb = xv.x * U0 + xv.y * U1 + xv.z * U2 + xv.w * U3;
#pragma unroll
      for (int o = 1; o < 16; o <<= 1) {
        aa += __shfl_xor(aa, o);
        bb += __shfl_xor(bb, o);
      }
      if (c4 == 0) {
        u2_s[lrow] = aa;
        tj_s[lrow] = bb;
      }
    }
  }

  const float md = slots_max(maxslots, lane);
  const float mdist = fast_sqrt(md);
  const float r1c = fminf(r1in[0], mdist);
  const float r2c = fminf(r2in[0], mdist);
  const float i1x2 = 2.f / r1c;
  const float i2x2 = 2.f / r2c;

  f32x4 zero4 = {0.f, 0.f, 0.f, 0.f};
  f32x4 acc[4][4];
#pragma unroll
  for (int jt = 0; jt < 4; ++jt)
#pragma unroll
    for (int pt = 0; pt < 4; ++pt) acc[jt][pt] = zero4;
  float sb[4] = {0.f, 0.f, 0.f, 0.f};

  const int iw0 = ibase + w * 16;
  bf16x8 a0 = ld8(xb + (iw0 + l16) * 64 + quad * 8);
  bf16x8 a1 = ld8(xb + (iw0 + l16) * 64 + 32 + quad * 8);
  float4 qi = *reinterpret_cast<const float4*>(&sq[iw0 + quad * 4]);
  s16x4 bfr[4];
#pragma unroll
  for (int pt = 0; pt < 4; ++pt)
    bfr[pt] = *reinterpret_cast<const s16x4*>(xT + (pt * 16 + l16) * NROW + iw0 + quad * 4);
  __syncthreads();  // xjt, ujt, tj_s/u2_s ready

  float sqj[4], tj[4], u2j[4];
#pragma unroll
  for (int jt = 0; jt < 4; ++jt) {
    sqj[jt] = sq[j0 + jt * 16 + l16];
    tj[jt] = tj_s[jt * 16 + l16];
    u2j[jt] = u2_s[jt * 16 + l16];
  }

#pragma unroll
  for (int s = 0; s < 8; ++s) {
    bf16x8 na0, na1;
    float4 nqi;
    s16x4 nbfr[4];
    if (s < 7) {
      const int irn = ibase + (s + 1) * 64 + w * 16;
      na0 = ld8(xb + (irn + l16) * 64 + quad * 8);
      na1 = ld8(xb + (irn + l16) * 64 + 32 + quad * 8);
      nqi = *reinterpret_cast<const float4*>(&sq[irn + quad * 4]);
#pragma unroll
      for (int pt = 0; pt < 4; ++pt)
        nbfr[pt] =
            *reinterpret_cast<const s16x4*>(xT + (pt * 16 + l16) * NROW + irn + quad * 4);
    }
#pragma unroll
    for (int jt = 0; jt < 4; ++jt) {
      bf16x8 xf0 = ld8(&xjt[(jt * 16 + l16) * LDW + quad * 8]);
      bf16x8 uf0 = ld8(&ujt[(jt * 16 + l16) * LDW + quad * 8]);
      bf16x8 xf1 = ld8(&xjt[(jt * 16 + l16) * LDW + 32 + quad * 8]);
      bf16x8 uf1 = ld8(&ujt[(jt * 16 + l16) * LDW + 32 + quad * 8]);
      f32x4 gxx = zero4, gxu = zero4;
      gxx = mfma16(a0, xf0, gxx);
      gxu = mfma16(a0, uf0, gxu);
      gxx = mfma16(a1, xf1, gxx);
      gxu = mfma16(a1, uf1, gxu);
      const float tjv = tj[jt], u2jv = u2j[jt], sjv = sqj[jt];
      s16x4 wf;
#pragma unroll
      for (int r = 0; r < 4; ++r) {
        float d2 = fmaxf(fmaf(-2.f, gxx[r], qi[r] + sjv), 0.f);
        float c = gxu[r] - tjv;
        float du2 = fmaxf(c * c * u2jv, 1e-6f);
        float dv2 = fmaxf(d2 - du2, 1e-6f);
        float du = fast_sqrt(du2);
        float dv = fast_sqrt(dv2);
        // w(d) = (1 - t^2)^3, t = clamp(2d/r - 1, 0, 1): exact on all 3 branches
        float q1 = fminf(fmaxf(fmaf(dv, i1x2, -1.f), 0.f), 1.f);
        float b1 = fmaf(-q1, q1, 1.f);
        float w1 = b1 * b1 * b1;
        float q2 = fminf(fmaxf(fmaf(du, i2x2, -1.f), 0.f), 1.f);
        float b2 = fmaf(-q2, q2, 1.f);
        float w2 = b2 * b2 * b2;
        float wv = w1 * w2;
        sb[jt] += wv;
        wf[r] = (short)f2bf_t(wv);
      }
#pragma unroll
      for (int pt = 0; pt < 4; ++pt) acc[jt][pt] = mfma16k(wf, bfr[pt], acc[jt][pt]);
    }
    if (s < 7) {
      a0 = na0;
      a1 = na1;
      qi = nqi;
#pragma unroll
      for (int pt = 0; pt < 4; ++pt) bfr[pt] = nbfr[pt];
    }
  }

  float* ep = ez_part + (size_t)blockIdx.y * SLICE;
#pragma unroll
  for (int rd = 0; rd < 2; ++rd) {
    __syncthreads();
#pragma unroll
    for (int jh = 0; jh < 2; ++jh) {
      const int jt = rd * 2 + jh;
#pragma unroll
      for (int pt = 0; pt < 4; ++pt)
#pragma unroll
        for (int r = 0; r < 4; ++r)
          redbuf[w][(jh * 16 + quad * 4 + r) * RDW + pt * 16 + l16] = acc[jt][pt][r];
    }
    __syncthreads();
#pragma unroll
    for (int jj = 0; jj < 8; ++jj) {
      const int jrel = w * 8 + jj;
      float v = redbuf[0][jrel * RDW + lane] + redbuf[1][jrel * RDW + lane] +
                redbuf[2][jrel * RDW + lane] + redbuf[3][jrel * RDW + lane];
      ep[(j0 + rd * 32 + jrel) * 64 + lane] = v;
    }
  }
#pragma unroll
  for (int jt = 0; jt < 4; ++jt) {
    float v = sb[jt];
    v += __shfl_xor(v, 16);
    v += __shfl_xor(v, 32);
    if (lane < 16) sred[w][jt * 16 + lane] = v;
  }
  __syncthreads();
  if (tid < 64)
    s_part[blockIdx.y * NROW + j0 + tid] =
        sred[0][tid] + sred[1][tid] + sred[2][tid] + sred[3][tid];
}

// ---------------- finish: float4 reduce partials, NaN -> x ----------------
__global__ __launch_bounds__(256) void finish_kernel(const float* __restrict__ x,
                                                     const float* __restrict__ ez_part,
                                                     const float* __restrict__ s_part,
                                                     float* __restrict__ out) {
  const int tid = threadIdx.x;
  const int row = blockIdx.x * 16 + (tid >> 4);
  const int c4 = tid & 15;
  float4 num = {0.f, 0.f, 0.f, 0.f};
  float den = 0.f;
#pragma unroll
  for (int y = 0; y < NSPLIT; ++y) {
    float4 v = *reinterpret_cast<const float4*>(&ez_part[(size_t)y * SLICE + row * 64 + c4 * 4]);
    num.x += v.x; num.y += v.y; num.z += v.z; num.w += v.w;
    den += s_part[y * NROW + row];
  }
  float4 xv = *reinterpret_cast<const float4*>(&x[row * 64 + c4 * 4]);
  float inv = 1.f / den;
  float4 o;
  o.x = num.x * inv; o.y = num.y * inv; o.z = num.z * inv; o.w = num.w * inv;
  if (o.x != o.x) o.x = xv.x;
  if (o.y != o.y) o.y = xv.y;
  if (o.z != o.z) o.z = xv.z;
  if (o.w != o.w) o.w = xv.w;
  *reinterpret_cast<float4*>(&out[row * 64 + c4 * 4]) = o;
}

extern "C" void kernel_launch(void* const* d_in, const int* in_sizes, int n_in,
                              void* d_out, int out_size, void* d_ws, size_t ws_size,
                              hipStream_t stream) {
  (void)in_sizes; (void)n_in; (void)out_size;
  const float* x = (const float*)d_in[0];
  const float* r0 = (const float*)d_in[1];
  const float* r1 = (const float*)d_in[2];
  const float* r2 = (const float*)d_in[3];
  float* out = (float*)d_out;
  char* ws = (char*)d_ws;

  u16* xb = (u16*)(ws);                              // 512 KB
  u16* xT = (u16*)(ws + (512 << 10));                // 512 KB
  float* sq = (float*)(ws + (1536 << 10));           // 16 KB
  float* maxslots = (float*)(ws + (1584 << 10));     // 4 KB
  float* s_part_a = (float*)(ws + (1588 << 10));     // 256 KB (128 used)
  float* s_part_b = (float*)(ws + (1844 << 10));     // 256 KB (128 used)
  float* part_mu = (float*)(ws + (2100 << 10));      // 8 MB
  float* part_ez = (float*)(ws + ((2100 << 10) + ((size_t)8 << 20)));  // 8 MB
  size_t need = ((size_t)2100 << 10) + ((size_t)16 << 20);
  if (ws_size < need) return;

  prep_kernel<<<64, 256, 0, stream>>>(x, xb, xT, sq, maxslots);
  pass1_max<<<dim3(64, 16), 256, 0, stream>>>(xb, sq, maxslots, r0, r1, r2);
  pass2_kernel<<<dim3(64, NSPLIT), 256, 0, stream>>>(xb, xT, sq, maxslots, r0, part_mu,
                                                     s_part_a);
  pass3_kernel<<<dim3(64, NSPLIT), 256, 0, stream>>>(xb, xT, sq, part_mu, s_part_a, maxslots,
                                                     r1, r2, x, part_ez, s_part_b);
  finish_kernel<<<256, 256, 0, stream>>>(x, part_ez, s_part_b, out);
}